// Round 14
// baseline (930.097 us; speedup 1.0000x reference)
//
#include <hip/hip_runtime.h>
#include <hip/hip_bf16.h>
#include <cstdint>

// CausalScaledDotAttention: B=16, S=Q=2048, H=1024, fp32 in/out.
// d_out = [ context fp32 B*S*H | attention^T fp32 B*S*Q ].
// ws layout (~262.5 MB, regions reused):
//   0      : xq bf16 (64MB)   -> kb bf16 after q-proj
//   64M    : xk bf16 (64MB)   -> vT bf16 [B][H][S] after k-proj
//   128M   : xv bf16 (64MB)   -> probs-low after vT-proj
//   192M   : qb bf16 (64MB)   -> probs-high after scores
//   256M   : Wq,Wk,Wv bf16 (3 x 2MB)
//   262.25M: mbuf,lbuf fp32 (2 x 128KB)

typedef unsigned short u16;
typedef __bf16 bfrag __attribute__((ext_vector_type(8)));
typedef float f32x4 __attribute__((ext_vector_type(4)));

#define DEVI __device__ __forceinline__

DEVI u16 f2bf(float f) {
  unsigned u = __builtin_bit_cast(unsigned, f);
  u += 0x7FFFu + ((u >> 16) & 1u);
  return (u16)(u >> 16);
}

DEVI void g2l16(const void* g, void* l) {
  __builtin_amdgcn_global_load_lds(
      (const __attribute__((address_space(1))) void*)g,
      (__attribute__((address_space(3))) void*)l, 16, 0, 0);
}

__global__ void cast_f32_to_bf16(const float* __restrict__ in, u16* __restrict__ out, long n4) {
  long i = (long)blockIdx.x * blockDim.x + threadIdx.x;
  long stride = (long)gridDim.x * blockDim.x;
  for (long j = i; j < n4; j += stride) {
    float4 v = ((const float4*)in)[j];
    ushort4 o;
    o.x = f2bf(v.x); o.y = f2bf(v.y); o.z = f2bf(v.z); o.w = f2bf(v.w);
    ((ushort4*)out)[j] = o;
  }
}

// 128x128-tile NT GEMM, 256 threads = 4 waves (2M x 2N), per-wave 64x64 out.
// m97 2-barrier structure: single LDS buffer (A 16KB + B 16KB = 32KB),
// stage(kt) -> sync -> 32 MFMA -> sync. Multi-block co-residency (~2.5
// blocks/CU at ~100 VGPR / 32KB LDS) provides implicit wave-level overlap --
// the proven 874-912 TF structure. [256^2 tile = 1 block/CU, no co-residency,
// ~650 TF avg (R6=815us total); all explicit-pipeline grafts on it regressed
// (r7 -52, r7b -102, r8 -52). This round: single-variable switch to 128^2.]
// T2 chunk swizzle both-sides (L[row][cc] = G[row][cc^(row&7)], 16B chunks;
// conflicts=0 verified in R5). T1 bijective XCD swizzle (nwg%8==0).
// CAUSAL: 0 none; 1 skip tile if m0 > n0+127 (scores^T: m=s,n=q);
//         2 K-cap at m0+128 (PV), by flipped so heavy tiles launch first.
template<int OUT_F32, int BIAS_MODE, int CAUSAL>
__global__ __launch_bounds__(256)
void gemm_nt128(const u16* __restrict__ A, const u16* __restrict__ B,
                void* __restrict__ Cv, const float* __restrict__ bias,
                float scale, int K, long sA, long sB, long sC, int ldc,
                int gx, int gy)
{
  int nwg = gridDim.x * gridDim.y * gridDim.z;
  int hbid = blockIdx.x + gridDim.x * (blockIdx.y + gridDim.y * blockIdx.z);
  int cpx = nwg >> 3;
  int l = (hbid & 7) * cpx + (hbid >> 3);
  int bx = l % gx;
  int rest = l / gx;
  int by = rest % gy;
  int bz = rest / gy;
  if (CAUSAL == 2) by = (gy - 1) - by;   // heavy K first (LPT pairing)

  long n0 = (long)bx * 128;
  long m0 = (long)by * 128;
  if (CAUSAL == 1 && m0 > n0 + 127) return;
  const u16* Ab = A + (long)bz * sA;
  const u16* Bb = B + (long)bz * sB;

  __shared__ __align__(16) u16 lA[128 * 64];
  __shared__ __align__(16) u16 lB[128 * 64];

  int tid = threadIdx.x;
  int lane = tid & 63;
  int wid = tid >> 6;       // 0..3
  int wr = wid >> 1, wc = wid & 1;

  f32x4 acc[4][4] = {};

  int kmax = (CAUSAL == 2) ? ((K < m0 + 128) ? K : (int)(m0 + 128)) : K;
  int nkt = kmax >> 6;      // BK = 64

  for (int kt = 0; kt < nkt; ++kt) {
    long k0 = (long)kt << 6;
    #pragma unroll
    for (int i = 0; i < 4; ++i) {
      int c = tid + (i << 8);          // 16B-chunk index 0..1023
      int row = c >> 3;                // 8 chunks per 64-col row
      int sc = (c & 7) ^ (row & 7);    // pre-swizzled source chunk
      g2l16(Ab + (m0 + row) * (long)K + k0 + (sc << 3), (char*)lA + c * 16);
      g2l16(Bb + (n0 + row) * (long)K + k0 + (sc << 3), (char*)lB + c * 16);
    }
    __syncthreads();
    #pragma unroll
    for (int k2 = 0; k2 < 2; ++k2) {
      int kbc = (k2 << 2) + (lane >> 4);        // logical chunk 0..7
      int rsel = lane & 15;
      bfrag af[4], bf[4];
      #pragma unroll
      for (int f = 0; f < 4; ++f) {
        int ra = wr * 64 + f * 16 + rsel;
        af[f] = *(const bfrag*)((const char*)lA + ra * 128 + ((kbc ^ (ra & 7)) << 4));
      }
      #pragma unroll
      for (int f = 0; f < 4; ++f) {
        int rb = wc * 64 + f * 16 + rsel;
        bf[f] = *(const bfrag*)((const char*)lB + rb * 128 + ((kbc ^ (rb & 7)) << 4));
      }
      #pragma unroll
      for (int mi = 0; mi < 4; ++mi)
        #pragma unroll
        for (int ni = 0; ni < 4; ++ni)
          acc[mi][ni] = __builtin_amdgcn_mfma_f32_16x16x32_bf16(af[mi], bf[ni], acc[mi][ni], 0, 0, 0);
    }
    __syncthreads();
  }

  // epilogue: C/D layout col=lane&15, row=(lane>>4)*4+i
  long cmb = m0 + wr * 64 + (lane >> 4) * 4;
  long cnb = n0 + wc * 64 + (lane & 15);
  #pragma unroll
  for (int mi = 0; mi < 4; ++mi) {
    #pragma unroll
    for (int ni = 0; ni < 4; ++ni) {
      f32x4 v = acc[mi][ni];
      long col = cnb + ni * 16;
      #pragma unroll
      for (int i = 0; i < 4; ++i) {
        long row = cmb + mi * 16 + i;
        float x = v[i] * scale;
        if (BIAS_MODE == 1) x += bias[col];
        if (BIAS_MODE == 2) x += bias[row];
        long cidx = (long)bz * sC + row * ldc + col;
        if (OUT_F32) ((float*)Cv)[cidx] = x;
        else         ((u16*)Cv)[cidx] = f2bf(x);
      }
    }
  }
}

// Parallel per-(b,q) row max & sum(exp) over s<=q; att stored [b][s][q].
// 512 threads = 64 q-lanes x 8 s-groups; branch-free online (m,l), LDS merge.
__global__ __launch_bounds__(512)
void softmax_stats(const float* __restrict__ att, float* __restrict__ mo,
                   float* __restrict__ lo, int S) {
  int b  = blockIdx.y;
  int q0 = blockIdx.x * 64;
  int t  = threadIdx.x;
  int ql = t & 63;
  int grp = t >> 6;            // 0..7
  int q = q0 + ql;
  const float* a = att + (long)b * S * S + q;
  int send = q0 + 64;
  float m = -3.0e38f, l = 0.0f;
  for (int s = grp; s < send; s += 8) {
    float v = (s <= q) ? a[(long)s * S] : -3.0e38f;
    float mn = fmaxf(m, v);
    l = l * __expf(m - mn) + __expf(v - mn);
    m = mn;
  }
  __shared__ float sm[8][64], sl[8][64];
  sm[grp][ql] = m;
  sl[grp][ql] = l;
  __syncthreads();
  if (t < 64) {
    float M = sm[0][t];
    #pragma unroll
    for (int g = 1; g < 8; ++g) M = fmaxf(M, sm[g][t]);
    float L = 0.0f;
    #pragma unroll
    for (int g = 0; g < 8; ++g) L += sl[g][t] * __expf(sm[g][t] - M);
    mo[(long)b * S + q0 + t] = M;
    lo[(long)b * S + q0 + t] = L;
  }
}

// normalize att in place ([b][s][q], zeros for s>q) and emit bf16 probs [b][q][s].
// probs writes skipped for tiles PV never reads (s0 >= (q0&~127)+128, PV K-cap).
__global__ void norm_transpose(float* __restrict__ att, const float* __restrict__ ms,
                               const float* __restrict__ ls, u16* __restrict__ probs, int S) {
  int b  = blockIdx.z;
  int q0 = blockIdx.x * 64;
  int s0 = blockIdx.y * 64;
  float* a = att + (long)b * S * S;
  u16* p = probs + (long)b * S * S;
  int tid = threadIdx.x;
  bool needp = s0 < ((q0 & ~127) + 128);   // PV K-cap coverage (128 tiles)

  if (s0 > q0 + 63) {  // fully masked tile
    float4 z = make_float4(0.f, 0.f, 0.f, 0.f);
    ushort4 zu; zu.x = zu.y = zu.z = zu.w = 0;
    #pragma unroll
    for (int it = 0; it < 4; ++it) {
      int j = tid + it * 256; int row = j >> 4; int c4 = (j & 15) * 4;
      *(float4*)&a[(long)(s0 + row) * S + q0 + c4] = z;
      if (needp) *(ushort4*)&p[(long)(q0 + row) * S + s0 + c4] = zu;
    }
    return;
  }

  __shared__ float t[64][65];
  __shared__ float lm[64], lr[64];
  if (tid < 64) {
    lm[tid] = ms[(long)b * S + q0 + tid];
    lr[tid] = 1.0f / ls[(long)b * S + q0 + tid];
  }
  __syncthreads();

  #pragma unroll
  for (int it = 0; it < 4; ++it) {
    int j = tid + it * 256; int row = j >> 4; int c4 = (j & 15) * 4;
    int s = s0 + row;
    float4 v = *(const float4*)&a[(long)s * S + q0 + c4];
    float vv[4] = {v.x, v.y, v.z, v.w};
    float oo[4];
    #pragma unroll
    for (int e = 0; e < 4; ++e) {
      int q = q0 + c4 + e;
      float pv = (s <= q) ? __expf(vv[e] - lm[c4 + e]) * lr[c4 + e] : 0.0f;
      oo[e] = pv;
      t[row][c4 + e] = pv;
    }
    float4 ov; ov.x = oo[0]; ov.y = oo[1]; ov.z = oo[2]; ov.w = oo[3];
    *(float4*)&a[(long)s * S + q0 + c4] = ov;
  }
  __syncthreads();

  #pragma unroll
  for (int it = 0; it < 4; ++it) {
    int j = tid + it * 256; int qrow = j >> 4; int sc4 = (j & 15) * 4;
    ushort4 ov;
    ov.x = f2bf(t[sc4 + 0][qrow]);
    ov.y = f2bf(t[sc4 + 1][qrow]);
    ov.z = f2bf(t[sc4 + 2][qrow]);
    ov.w = f2bf(t[sc4 + 3][qrow]);
    *(ushort4*)&p[(long)(q0 + qrow) * S + s0 + sc4] = ov;
  }
}

extern "C" void kernel_launch(void* const* d_in, const int* in_sizes, int n_in,
                              void* d_out, int out_size, void* d_ws, size_t ws_size,
                              hipStream_t stream) {
  const int B = 16, S = 2048, H = 1024;
  const long NE = (long)B * S * H;           // 33554432
  const float* Q  = (const float*)d_in[0];
  const float* Kk = (const float*)d_in[1];
  const float* V  = (const float*)d_in[2];
  const float* Wq = (const float*)d_in[3];
  const float* bq = (const float*)d_in[4];
  const float* Wk = (const float*)d_in[5];
  const float* bk = (const float*)d_in[6];
  const float* Wv = (const float*)d_in[7];
  const float* bv = (const float*)d_in[8];

  char* ws = (char*)d_ws;
  u16* xq    = (u16*)ws;                     // 0..64M
  u16* xk    = (u16*)(ws + (64L << 20));     // 64..128M
  u16* xv    = (u16*)(ws + (128L << 20));    // 128..192M
  u16* qb    = (u16*)(ws + (192L << 20));    // 192..256M
  u16* kb    = (u16*)ws;                     // reuse xq (dead after q-proj)
  u16* vT    = (u16*)(ws + (64L << 20));     // reuse xk (dead after k-proj), [B][H][S]
  u16* probs = (u16*)(ws + (128L << 20));    // reuse xv+qb (dead by norm), [B][Q][S]
  u16* Wqb   = (u16*)(ws + (256L << 20));
  u16* Wkb   = (u16*)(ws + (256L << 20) + (2L << 20));
  u16* Wvb   = (u16*)(ws + (256L << 20) + (4L << 20));
  float* mbuf = (float*)(ws + (256L << 20) + (6L << 20));
  float* lbuf = (float*)(ws + (256L << 20) + (6L << 20) + (1L << 17));

  float* ctx = (float*)d_out;            // [B][Q][H]
  float* att = (float*)d_out + NE;       // [B][S][Q]

  // 1) casts fp32 -> bf16
  cast_f32_to_bf16<<<2048, 256, 0, stream>>>(Q,  xq, NE >> 2);
  cast_f32_to_bf16<<<2048, 256, 0, stream>>>(Kk, xk, NE >> 2);
  cast_f32_to_bf16<<<2048, 256, 0, stream>>>(V,  xv, NE >> 2);
  cast_f32_to_bf16<<<512, 256, 0, stream>>>(Wq, Wqb, ((long)H * H) >> 2);
  cast_f32_to_bf16<<<512, 256, 0, stream>>>(Wk, Wkb, ((long)H * H) >> 2);
  cast_f32_to_bf16<<<512, 256, 0, stream>>>(Wv, Wvb, ((long)H * H) >> 2);

  // 2) projections: q = xq@Wq^T+bq -> qb; k -> kb; v computed transposed -> vT
  gemm_nt128<0, 1, 0><<<dim3(8, 256, 1), 256, 0, stream>>>(
      xq, Wqb, qb, bq, 1.0f, H, 0, 0, 0, H, 8, 256);
  gemm_nt128<0, 1, 0><<<dim3(8, 256, 1), 256, 0, stream>>>(
      xk, Wkb, kb, bk, 1.0f, H, 0, 0, 0, H, 8, 256);
  gemm_nt128<0, 2, 0><<<dim3(16, 8, 16), 256, 0, stream>>>(
      Wvb, xv, vT, bv, 1.0f, H, 0, (long)S * H, (long)H * S, S, 16, 8);

  // 3) scores^T into d_out att region: att[b][s][q] = (k_s . q_q)/sqrt(H)
  gemm_nt128<1, 0, 1><<<dim3(16, 16, 16), 256, 0, stream>>>(
      kb, qb, att, nullptr, 0.03125f, H, (long)S * H, (long)S * H,
      (long)S * S, S, 16, 16);

  // 4) per-row softmax stats (parallel over s)
  softmax_stats<<<dim3(32, 16), 512, 0, stream>>>(att, mbuf, lbuf, S);

  // 5) normalize in place (+zero masked region), emit bf16 probs [b][q][s]
  norm_transpose<<<dim3(32, 32, 16), 256, 0, stream>>>(att, mbuf, lbuf, probs, S);

  // 6) context = probs @ v  (PV, causal K cap at m0+128, heavy-first order)
  gemm_nt128<1, 0, 2><<<dim3(8, 16, 16), 256, 0, stream>>>(
      probs, vT, ctx, nullptr, 1.0f, S, (long)S * S, (long)H * S,
      (long)S * H, H, 8, 16);
}

// Round 15
// 800.821 us; speedup vs baseline: 1.1614x; 1.1614x over previous
//
#include <hip/hip_runtime.h>
#include <hip/hip_bf16.h>
#include <cstdint>

// CausalScaledDotAttention: B=16, S=Q=2048, H=1024, fp32 in/out.
// d_out = [ context fp32 B*S*H | attention^T fp32 B*S*Q ].
// ws layout (~262.5 MB, regions reused):
//   0      : xq bf16 (64MB)   -> kb bf16 after q-proj
//   64M    : xk bf16 (64MB)   -> vT bf16 [B][H][S] after k-proj
//   128M   : xv bf16 (64MB)   -> probs-low after vT-proj
//   192M   : qb bf16 (64MB)   -> probs-high after scores
//   256M   : Wq,Wk,Wv bf16 (3 x 2MB)
//   262.25M: mbuf,lbuf fp32 (2 x 128KB)

typedef unsigned short u16;
typedef __bf16 bfrag __attribute__((ext_vector_type(8)));
typedef float f32x4 __attribute__((ext_vector_type(4)));

#define DEVI __device__ __forceinline__

DEVI u16 f2bf(float f) {
  unsigned u = __builtin_bit_cast(unsigned, f);
  u += 0x7FFFu + ((u >> 16) & 1u);
  return (u16)(u >> 16);
}

DEVI void g2l16(const void* g, void* l) {
  __builtin_amdgcn_global_load_lds(
      (const __attribute__((address_space(1))) void*)g,
      (__attribute__((address_space(3))) void*)l, 16, 0, 0);
}

__global__ void cast_f32_to_bf16(const float* __restrict__ in, u16* __restrict__ out, long n4) {
  long i = (long)blockIdx.x * blockDim.x + threadIdx.x;
  long stride = (long)gridDim.x * blockDim.x;
  for (long j = i; j < n4; j += stride) {
    float4 v = ((const float4*)in)[j];
    ushort4 o;
    o.x = f2bf(v.x); o.y = f2bf(v.y); o.z = f2bf(v.z); o.w = f2bf(v.w);
    ((ushort4*)out)[j] = o;
  }
}

// 256x256-tile NT GEMM, 512 threads = 8 waves (2M x 4N), per-wave 128x64 out.
// BK=64, 2-slot double buffer (128KB LDS -> 1 block/CU). 2-phase: stage
// K-tile t+1 (async global_load_lds) BEFORE computing tile t; ONE
// __syncthreads per K-tile. [R6/R13-proven 814-815us configuration.
// Session model: these GEMMs are operand-traffic-bound through L3
// (re-fetch ~ 1/BM+1/BN) -- 256^2 halves traffic vs 128^2 (R14: 930us);
// compute-schedule grafts are null-to-negative (r7 -52, r7b -102, r8 -52).]
// T2 chunk swizzle (conflicts=0 verified). T1 bijective XCD swizzle.
// FUSE_QK: gy doubled; by<gy/2 -> operand set 0 (A,B,bias,C), else set 1.
// CAUSAL: 0 none; 1 skip tile if m0 > n0+255 (scores^T: m=s,n=q);
//         2 K-cap at m0+256 (PV), by flipped so heavy tiles launch first.
template<int OUT_F32, int BIAS_MODE, int CAUSAL, int FUSE_QK>
__global__ __launch_bounds__(512, 2)
void gemm_nt256(const u16* __restrict__ A, const u16* __restrict__ B,
                void* __restrict__ Cv, const float* __restrict__ bias,
                const u16* __restrict__ A2, const u16* __restrict__ B2,
                void* __restrict__ Cv2, const float* __restrict__ bias2,
                float scale, int K, long sA, long sB, long sC, int ldc,
                int gx, int gy)
{
  int nwg = gridDim.x * gridDim.y * gridDim.z;
  int hbid = blockIdx.x + gridDim.x * (blockIdx.y + gridDim.y * blockIdx.z);
  int cpx = nwg >> 3;
  int l = (hbid & 7) * cpx + (hbid >> 3);
  int bx = l % gx;
  int rest = l / gx;
  int by = rest % gy;
  int bz = rest / gy;
  if (CAUSAL == 2) by = (gy - 1) - by;   // heavy K first (LPT pairing)

  if (FUSE_QK) {
    int half = gy >> 1;
    if (by >= half) {                    // second operand set
      by -= half;
      A = A2; B = B2; Cv = Cv2; bias = bias2;
    }
  }

  long n0 = (long)bx * 256;
  long m0 = (long)by * 256;
  if (CAUSAL == 1 && m0 > n0 + 255) return;
  const u16* Ab = A + (long)bz * sA;
  const u16* Bb = B + (long)bz * sB;

  __shared__ __align__(16) u16 lA[2][256 * 64];
  __shared__ __align__(16) u16 lB[2][256 * 64];

  int tid = threadIdx.x;
  int lane = tid & 63;
  int wid = tid >> 6;       // 0..7
  int wr = wid >> 2;        // 0..1 (M)
  int wc = wid & 3;         // 0..3 (N)

  f32x4 acc[8][4] = {};

  int kmax = (CAUSAL == 2) ? ((K < m0 + 256) ? K : (int)(m0 + 256)) : K;
  int nkt = kmax >> 6;      // BK = 64

  auto stage = [&](int kt, int bsel) {
    long k0 = (long)kt << 6;
    #pragma unroll
    for (int i = 0; i < 4; ++i) {
      int c = tid + (i << 9);          // 16B-chunk index 0..2047
      int row = c >> 3;                // 8 chunks per 64-col row
      int sc = (c & 7) ^ (row & 7);    // pre-swizzled source chunk
      g2l16(Ab + (m0 + row) * (long)K + k0 + (sc << 3), (char*)lA[bsel] + c * 16);
      g2l16(Bb + (n0 + row) * (long)K + k0 + (sc << 3), (char*)lB[bsel] + c * 16);
    }
  };

  stage(0, 0);
  __syncthreads();
  int cur = 0;
  for (int t = 0; t < nkt; ++t) {
    if (t + 1 < nkt) stage(t + 1, cur ^ 1);   // prefetch flies under MFMA
    const char* la = (const char*)lA[cur];
    const char* lb = (const char*)lB[cur];
    #pragma unroll
    for (int k2 = 0; k2 < 2; ++k2) {
      int kbc = (k2 << 2) + (lane >> 4);        // logical chunk 0..7
      int rsel = lane & 15;
      bfrag af[8], bf[4];
      #pragma unroll
      for (int f = 0; f < 8; ++f) {
        int ra = wr * 128 + f * 16 + rsel;
        af[f] = *(const bfrag*)(la + ra * 128 + ((kbc ^ (ra & 7)) << 4));
      }
      #pragma unroll
      for (int f = 0; f < 4; ++f) {
        int rb = wc * 64 + f * 16 + rsel;
        bf[f] = *(const bfrag*)(lb + rb * 128 + ((kbc ^ (rb & 7)) << 4));
      }
      #pragma unroll
      for (int mi = 0; mi < 8; ++mi)
        #pragma unroll
        for (int ni = 0; ni < 4; ++ni)
          acc[mi][ni] = __builtin_amdgcn_mfma_f32_16x16x32_bf16(af[mi], bf[ni], acc[mi][ni], 0, 0, 0);
    }
    __syncthreads();   // drains staging (implicit vmcnt) + slot-reuse fence
    cur ^= 1;
  }

  // epilogue: C/D layout col=lane&15, row=(lane>>4)*4+i
  long cmb = m0 + wr * 128 + (lane >> 4) * 4;
  long cnb = n0 + wc * 64 + (lane & 15);
  #pragma unroll
  for (int mi = 0; mi < 8; ++mi) {
    #pragma unroll
    for (int ni = 0; ni < 4; ++ni) {
      f32x4 v = acc[mi][ni];
      long col = cnb + ni * 16;
      #pragma unroll
      for (int i = 0; i < 4; ++i) {
        long row = cmb + mi * 16 + i;
        float x = v[i] * scale;
        if (BIAS_MODE == 1) x += bias[col];
        if (BIAS_MODE == 2) x += bias[row];
        long cidx = (long)bz * sC + row * ldc + col;
        if (OUT_F32) ((float*)Cv)[cidx] = x;
        else         ((u16*)Cv)[cidx] = f2bf(x);
      }
    }
  }
}

// Parallel per-(b,q) row max & sum(exp) over s<=q; att stored [b][s][q].
// 512 threads = 64 q-lanes x 8 s-groups; branch-free online (m,l), LDS merge.
__global__ __launch_bounds__(512)
void softmax_stats(const float* __restrict__ att, float* __restrict__ mo,
                   float* __restrict__ lo, int S) {
  int b  = blockIdx.y;
  int q0 = blockIdx.x * 64;
  int t  = threadIdx.x;
  int ql = t & 63;
  int grp = t >> 6;            // 0..7
  int q = q0 + ql;
  const float* a = att + (long)b * S * S + q;
  int send = q0 + 64;
  float m = -3.0e38f, l = 0.0f;
  for (int s = grp; s < send; s += 8) {
    float v = (s <= q) ? a[(long)s * S] : -3.0e38f;
    float mn = fmaxf(m, v);
    l = l * __expf(m - mn) + __expf(v - mn);
    m = mn;
  }
  __shared__ float sm[8][64], sl[8][64];
  sm[grp][ql] = m;
  sl[grp][ql] = l;
  __syncthreads();
  if (t < 64) {
    float M = sm[0][t];
    #pragma unroll
    for (int g = 1; g < 8; ++g) M = fmaxf(M, sm[g][t]);
    float L = 0.0f;
    #pragma unroll
    for (int g = 0; g < 8; ++g) L += sl[g][t] * __expf(sm[g][t] - M);
    mo[(long)b * S + q0 + t] = M;
    lo[(long)b * S + q0 + t] = L;
  }
}

// normalize att in place ([b][s][q], zeros for s>q) and emit bf16 probs [b][q][s].
// probs writes skipped for tiles PV never reads (s0 >= (q0&~255)+256, PV K-cap).
__global__ void norm_transpose(float* __restrict__ att, const float* __restrict__ ms,
                               const float* __restrict__ ls, u16* __restrict__ probs, int S) {
  int b  = blockIdx.z;
  int q0 = blockIdx.x * 64;
  int s0 = blockIdx.y * 64;
  float* a = att + (long)b * S * S;
  u16* p = probs + (long)b * S * S;
  int tid = threadIdx.x;
  bool needp = s0 < ((q0 & ~255) + 256);   // PV K-cap coverage (256 tiles)

  if (s0 > q0 + 63) {  // fully masked tile
    float4 z = make_float4(0.f, 0.f, 0.f, 0.f);
    ushort4 zu; zu.x = zu.y = zu.z = zu.w = 0;
    #pragma unroll
    for (int it = 0; it < 4; ++it) {
      int j = tid + it * 256; int row = j >> 4; int c4 = (j & 15) * 4;
      *(float4*)&a[(long)(s0 + row) * S + q0 + c4] = z;
      if (needp) *(ushort4*)&p[(long)(q0 + row) * S + s0 + c4] = zu;
    }
    return;
  }

  __shared__ float t[64][65];
  __shared__ float lm[64], lr[64];
  if (tid < 64) {
    lm[tid] = ms[(long)b * S + q0 + tid];
    lr[tid] = 1.0f / ls[(long)b * S + q0 + tid];
  }
  __syncthreads();

  #pragma unroll
  for (int it = 0; it < 4; ++it) {
    int j = tid + it * 256; int row = j >> 4; int c4 = (j & 15) * 4;
    int s = s0 + row;
    float4 v = *(const float4*)&a[(long)s * S + q0 + c4];
    float vv[4] = {v.x, v.y, v.z, v.w};
    float oo[4];
    #pragma unroll
    for (int e = 0; e < 4; ++e) {
      int q = q0 + c4 + e;
      float pv = (s <= q) ? __expf(vv[e] - lm[c4 + e]) * lr[c4 + e] : 0.0f;
      oo[e] = pv;
      t[row][c4 + e] = pv;
    }
    float4 ov; ov.x = oo[0]; ov.y = oo[1]; ov.z = oo[2]; ov.w = oo[3];
    *(float4*)&a[(long)s * S + q0 + c4] = ov;
  }
  __syncthreads();

  #pragma unroll
  for (int it = 0; it < 4; ++it) {
    int j = tid + it * 256; int qrow = j >> 4; int sc4 = (j & 15) * 4;
    ushort4 ov;
    ov.x = f2bf(t[sc4 + 0][qrow]);
    ov.y = f2bf(t[sc4 + 1][qrow]);
    ov.z = f2bf(t[sc4 + 2][qrow]);
    ov.w = f2bf(t[sc4 + 3][qrow]);
    *(ushort4*)&p[(long)(q0 + qrow) * S + s0 + sc4] = ov;
  }
}

extern "C" void kernel_launch(void* const* d_in, const int* in_sizes, int n_in,
                              void* d_out, int out_size, void* d_ws, size_t ws_size,
                              hipStream_t stream) {
  const int B = 16, S = 2048, H = 1024;
  const long NE = (long)B * S * H;           // 33554432
  const float* Q  = (const float*)d_in[0];
  const float* Kk = (const float*)d_in[1];
  const float* V  = (const float*)d_in[2];
  const float* Wq = (const float*)d_in[3];
  const float* bq = (const float*)d_in[4];
  const float* Wk = (const float*)d_in[5];
  const float* bk = (const float*)d_in[6];
  const float* Wv = (const float*)d_in[7];
  const float* bv = (const float*)d_in[8];

  char* ws = (char*)d_ws;
  u16* xq    = (u16*)ws;                     // 0..64M
  u16* xk    = (u16*)(ws + (64L << 20));     // 64..128M
  u16* xv    = (u16*)(ws + (128L << 20));    // 128..192M
  u16* qb    = (u16*)(ws + (192L << 20));    // 192..256M
  u16* kb    = (u16*)ws;                     // reuse xq (dead after q-proj)
  u16* vT    = (u16*)(ws + (64L << 20));     // reuse xk (dead after k-proj), [B][H][S]
  u16* probs = (u16*)(ws + (128L << 20));    // reuse xv+qb (dead by norm), [B][Q][S]
  u16* Wqb   = (u16*)(ws + (256L << 20));
  u16* Wkb   = (u16*)(ws + (256L << 20) + (2L << 20));
  u16* Wvb   = (u16*)(ws + (256L << 20) + (4L << 20));
  float* mbuf = (float*)(ws + (256L << 20) + (6L << 20));
  float* lbuf = (float*)(ws + (256L << 20) + (6L << 20) + (1L << 17));

  float* ctx = (float*)d_out;            // [B][Q][H]
  float* att = (float*)d_out + NE;       // [B][S][Q]

  // 1) casts fp32 -> bf16
  cast_f32_to_bf16<<<2048, 256, 0, stream>>>(Q,  xq, NE >> 2);
  cast_f32_to_bf16<<<2048, 256, 0, stream>>>(Kk, xk, NE >> 2);
  cast_f32_to_bf16<<<2048, 256, 0, stream>>>(V,  xv, NE >> 2);
  cast_f32_to_bf16<<<512, 256, 0, stream>>>(Wq, Wqb, ((long)H * H) >> 2);
  cast_f32_to_bf16<<<512, 256, 0, stream>>>(Wk, Wkb, ((long)H * H) >> 2);
  cast_f32_to_bf16<<<512, 256, 0, stream>>>(Wv, Wvb, ((long)H * H) >> 2);

  // NOTE: k-proj writes kb which aliases xq -- safe ONLY because the fused
  // dispatch orders nothing between halves... it does NOT: q-proj (reads xq)
  // and k-proj (writes kb==xq) cannot run in one dispatch. Keep kb out of
  // the q half's inputs: q half reads xq+Wqb, writes qb; k half reads xk+Wkb,
  // writes kb==xq. Blocks of the two halves may interleave arbitrarily --
  // a k-half block could overwrite an xq row before a q-half block reads it.
  // => use a DISJOINT destination for k: write kb2 at 128..192M? That region
  // holds xv (needed later). Resolution: fused dispatch writes k-output to
  // qb-adjacent scratch is unavailable; therefore run k-proj's OUTPUT to the
  // original kb region only AFTER q half consumed xq. Simplest safe fusion:
  // fuse q-proj with V-PROJ instead (disjoint in/out: q reads xq/Wqb writes
  // qb; v reads xv/Wvb writes vT). k-proj stays separate.
  // (comment retained as the aliasing audit)

  // 2a) fused dispatch: q-proj (set 0) + v-proj-shaped half is NOT geometry-
  //     compatible; fuse q-proj + k-proj is unsafe (kb aliases xq).
  //     => fuse k-proj LAST with nothing; instead order: k-proj first
  //     (reads xk, writes kb==xq? NO - q-proj hasn't read xq yet).
  // Final safe plan: move kb to the qb region and qb to the kb region so
  // outputs don't alias inputs still needed: q-proj writes qb(192..256M),
  // k-proj writes kb2 = xk region? xk is k-proj's own input. No.
  // Conclusion: aliasing forbids the q/k fusion under ws reuse. Run the
  // proven serial order (R13-exact).
  gemm_nt256<0, 1, 0, 0><<<dim3(4, 128, 1), 512, 0, stream>>>(
      xq, Wqb, qb, bq, nullptr, nullptr, nullptr, nullptr,
      1.0f, H, 0, 0, 0, H, 4, 128);
  gemm_nt256<0, 1, 0, 0><<<dim3(4, 128, 1), 512, 0, stream>>>(
      xk, Wkb, kb, bk, nullptr, nullptr, nullptr, nullptr,
      1.0f, H, 0, 0, 0, H, 4, 128);
  gemm_nt256<0, 2, 0, 0><<<dim3(8, 4, 16), 512, 0, stream>>>(
      Wvb, xv, vT, bv, nullptr, nullptr, nullptr, nullptr,
      1.0f, H, 0, (long)S * H, (long)H * S, S, 8, 4);

  // 3) scores^T into d_out att region: att[b][s][q] = (k_s . q_q)/sqrt(H)
  gemm_nt256<1, 0, 1, 0><<<dim3(8, 8, 16), 512, 0, stream>>>(
      kb, qb, att, nullptr, nullptr, nullptr, nullptr, nullptr,
      0.03125f, H, (long)S * H, (long)S * H, (long)S * S, S, 8, 8);

  // 4) per-row softmax stats (parallel over s)
  softmax_stats<<<dim3(32, 16), 512, 0, stream>>>(att, mbuf, lbuf, S);

  // 5) normalize in place (+zero masked region), emit bf16 probs [b][q][s]
  norm_transpose<<<dim3(32, 32, 16), 256, 0, stream>>>(att, mbuf, lbuf, probs, S);

  // 6) context = probs @ v  (PV, causal K cap at m0+256, heavy-first order)
  gemm_nt256<1, 0, 2, 0><<<dim3(4, 8, 16), 512, 0, stream>>>(
      probs, vT, ctx, nullptr, nullptr, nullptr, nullptr, nullptr,
      1.0f, S, (long)S * S, (long)H * S, (long)S * H, H, 4, 8);
}

// Round 16
// 728.398 us; speedup vs baseline: 1.2769x; 1.0994x over previous
//
#include <hip/hip_runtime.h>
#include <hip/hip_bf16.h>
#include <cstdint>

// CausalScaledDotAttention: B=16, S=Q=2048, H=1024, fp32 in/out.
// d_out = [ context fp32 B*S*H | attention^T fp32 B*S*Q ].
// ws layout (~266 MB, regions reused):
//   0      : xq bf16 (64MB)   -> kb bf16 after q-proj
//   64M    : xk bf16 (64MB)   -> vT bf16 [B][H][S] after k-proj
//   128M   : xv bf16 (64MB)   -> probs-low after vT-proj
//   192M   : qb bf16 (64MB)   -> probs-high after scores
//   256M   : Wq,Wk,Wv bf16 (3 x 2MB)
//   262M   : mbuf,lbuf fp32 (2 x 128KB)
//   263M   : pm,pl fp32 partial stats [B][8 s-tiles][2048 q] (2 x 1MB)

typedef unsigned short u16;
typedef __bf16 bfrag __attribute__((ext_vector_type(8)));
typedef float f32x4 __attribute__((ext_vector_type(4)));

#define DEVI __device__ __forceinline__

DEVI u16 f2bf(float f) {
  unsigned u = __builtin_bit_cast(unsigned, f);
  u += 0x7FFFu + ((u >> 16) & 1u);
  return (u16)(u >> 16);
}

DEVI void g2l16(const void* g, void* l) {
  __builtin_amdgcn_global_load_lds(
      (const __attribute__((address_space(1))) void*)g,
      (__attribute__((address_space(3))) void*)l, 16, 0, 0);
}

__global__ void cast_f32_to_bf16(const float* __restrict__ in, u16* __restrict__ out, long n4) {
  long i = (long)blockIdx.x * blockDim.x + threadIdx.x;
  long stride = (long)gridDim.x * blockDim.x;
  for (long j = i; j < n4; j += stride) {
    float4 v = ((const float4*)in)[j];
    ushort4 o;
    o.x = f2bf(v.x); o.y = f2bf(v.y); o.z = f2bf(v.z); o.w = f2bf(v.w);
    ((ushort4*)out)[j] = o;
  }
}

// 256x256-tile NT GEMM, 512 threads = 8 waves (2M x 4N), per-wave 128x64 out.
// BK=64, 2-slot double buffer (128KB LDS -> 1 block/CU). 2-phase: stage
// K-tile t+1 BEFORE computing tile t; ONE __syncthreads per K-tile.
// [R6/R13/R15-proven 800-815us configuration. Session model: operand-traffic
// bound through L3 (re-fetch ~ 1/BM+1/BN): 256^2 beats 128^2 (R14 930us);
// schedule grafts null-to-negative (r7 -52, r7b -102, r8 -52); NT stores and
// (512,1) bounds regressed (R9 +93us).]
// T2 chunk swizzle (conflicts=0 verified). T1 bijective XCD swizzle.
// CAUSAL=1 (scores^T, m=s n=q): masked tiles ZERO-FILL their att region
// (moves norm's masked writes into this dispatch's compute shadow) and skip.
// STATS=1: epilogue reduces acc into per-(s-tile,q) softmax partials (m,l)
// via masked two-pass + shfl_xor(16/32) + 4KB LDS combine (aliased onto lA).
// CAUSAL=2: PV K-cap at m0+256, by flipped so heavy tiles launch first.
template<int OUT_F32, int BIAS_MODE, int CAUSAL, int STATS>
__global__ __launch_bounds__(512, 2)
void gemm_nt256(const u16* __restrict__ A, const u16* __restrict__ B,
                void* __restrict__ Cv, const float* __restrict__ bias,
                float* __restrict__ pm, float* __restrict__ pl,
                float scale, int K, long sA, long sB, long sC, int ldc,
                int gx, int gy)
{
  int nwg = gridDim.x * gridDim.y * gridDim.z;
  int hbid = blockIdx.x + gridDim.x * (blockIdx.y + gridDim.y * blockIdx.z);
  int cpx = nwg >> 3;
  int l = (hbid & 7) * cpx + (hbid >> 3);
  int bx = l % gx;
  int rest = l / gx;
  int by = rest % gy;
  int bz = rest / gy;
  if (CAUSAL == 2) by = (gy - 1) - by;   // heavy K first (LPT pairing)

  long n0 = (long)bx * 256;
  long m0 = (long)by * 256;
  int tid = threadIdx.x;

  if (CAUSAL == 1 && m0 > n0 + 255) {
    // fully-masked tile: zero-fill att here (write BW is idle during the
    // compute-bound scores dispatch); no stats partials needed (the reduce
    // only reads s-tiles <= q-tile).
    float4 z = make_float4(0.f, 0.f, 0.f, 0.f);
    float* C = (float*)Cv + (long)bz * sC;
    #pragma unroll
    for (int i = 0; i < 32; ++i) {
      int e = tid + (i << 9);          // float4 index 0..16383
      int row = e >> 6;                // 64 float4 per 256-col row
      int c4 = (e & 63) << 2;
      *(float4*)&C[(m0 + row) * (long)ldc + n0 + c4] = z;
    }
    return;
  }

  const u16* Ab = A + (long)bz * sA;
  const u16* Bb = B + (long)bz * sB;

  __shared__ __align__(16) u16 lA[2][256 * 64];
  __shared__ __align__(16) u16 lB[2][256 * 64];

  int lane = tid & 63;
  int wid = tid >> 6;       // 0..7
  int wr = wid >> 2;        // 0..1 (M)
  int wc = wid & 3;         // 0..3 (N)

  f32x4 acc[8][4] = {};

  int kmax = (CAUSAL == 2) ? ((K < m0 + 256) ? K : (int)(m0 + 256)) : K;
  int nkt = kmax >> 6;      // BK = 64

  auto stage = [&](int kt, int bsel) {
    long k0 = (long)kt << 6;
    #pragma unroll
    for (int i = 0; i < 4; ++i) {
      int c = tid + (i << 9);          // 16B-chunk index 0..2047
      int row = c >> 3;                // 8 chunks per 64-col row
      int sc = (c & 7) ^ (row & 7);    // pre-swizzled source chunk
      g2l16(Ab + (m0 + row) * (long)K + k0 + (sc << 3), (char*)lA[bsel] + c * 16);
      g2l16(Bb + (n0 + row) * (long)K + k0 + (sc << 3), (char*)lB[bsel] + c * 16);
    }
  };

  stage(0, 0);
  __syncthreads();
  int cur = 0;
  for (int t = 0; t < nkt; ++t) {
    if (t + 1 < nkt) stage(t + 1, cur ^ 1);   // prefetch flies under MFMA
    const char* la = (const char*)lA[cur];
    const char* lb = (const char*)lB[cur];
    #pragma unroll
    for (int k2 = 0; k2 < 2; ++k2) {
      int kbc = (k2 << 2) + (lane >> 4);        // logical chunk 0..7
      int rsel = lane & 15;
      bfrag af[8], bf[4];
      #pragma unroll
      for (int f = 0; f < 8; ++f) {
        int ra = wr * 128 + f * 16 + rsel;
        af[f] = *(const bfrag*)(la + ra * 128 + ((kbc ^ (ra & 7)) << 4));
      }
      #pragma unroll
      for (int f = 0; f < 4; ++f) {
        int rb = wc * 64 + f * 16 + rsel;
        bf[f] = *(const bfrag*)(lb + rb * 128 + ((kbc ^ (rb & 7)) << 4));
      }
      #pragma unroll
      for (int mi = 0; mi < 8; ++mi)
        #pragma unroll
        for (int ni = 0; ni < 4; ++ni)
          acc[mi][ni] = __builtin_amdgcn_mfma_f32_16x16x32_bf16(af[mi], bf[ni], acc[mi][ni], 0, 0, 0);
    }
    __syncthreads();   // drains staging (implicit vmcnt) + slot-reuse fence
    cur ^= 1;
  }

  // epilogue: C/D layout col=lane&15, row=(lane>>4)*4+i
  long cmb = m0 + wr * 128 + (lane >> 4) * 4;
  long cnb = n0 + wc * 64 + (lane & 15);
  #pragma unroll
  for (int mi = 0; mi < 8; ++mi) {
    #pragma unroll
    for (int ni = 0; ni < 4; ++ni) {
      f32x4 v = acc[mi][ni];
      long col = cnb + ni * 16;
      #pragma unroll
      for (int i = 0; i < 4; ++i) {
        long row = cmb + mi * 16 + i;
        float x = v[i] * scale;
        if (BIAS_MODE == 1) x += bias[col];
        if (BIAS_MODE == 2) x += bias[row];
        long cidx = (long)bz * sC + row * ldc + col;
        if (OUT_F32) ((float*)Cv)[cidx] = x;
        else         ((u16*)Cv)[cidx] = f2bf(x);
      }
    }
  }

  if (STATS) {
    // per-column (q) masked softmax partials over this tile's 256 s-rows.
    float* pml = (float*)&lA[0][0];    // [2][256] m then [2][256] l (4KB)
    #pragma unroll
    for (int ni = 0; ni < 4; ++ni) {
      long col = cnb + ni * 16;
      float m = -3.0e38f;
      #pragma unroll
      for (int mi = 0; mi < 8; ++mi)
        #pragma unroll
        for (int i = 0; i < 4; ++i) {
          long row = cmb + mi * 16 + i;
          float v = acc[mi][ni][i] * scale;
          if (row <= col) m = fmaxf(m, v);
        }
      float lsum = 0.f;
      #pragma unroll
      for (int mi = 0; mi < 8; ++mi)
        #pragma unroll
        for (int i = 0; i < 4; ++i) {
          long row = cmb + mi * 16 + i;
          float v = acc[mi][ni][i] * scale;
          lsum += (row <= col) ? __expf(v - m) : 0.f;   // guard: empty lane
        }
      // reduce across the 4 lanes holding this column (lane ^16, ^32)
      #pragma unroll
      for (int w = 16; w <= 32; w <<= 1) {
        float m2 = __shfl_xor(m, w);
        float l2 = __shfl_xor(lsum, w);
        float M = fmaxf(m, m2);
        lsum = lsum * __expf(m - M) + l2 * __expf(m2 - M);
        m = M;
      }
      if ((lane >> 4) == 0) {
        int tcol = wc * 64 + ni * 16 + lane;
        pml[wr * 256 + tcol] = m;
        pml[512 + wr * 256 + tcol] = lsum;
      }
    }
    __syncthreads();
    if (tid < 256) {
      float ma = pml[tid], mb2 = pml[256 + tid];
      float la_ = pml[512 + tid], lb_ = pml[768 + tid];
      float M = fmaxf(ma, mb2);
      float L = la_ * __expf(ma - M) + lb_ * __expf(mb2 - M);
      long st = m0 >> 8;
      long qi = n0 + tid;
      pm[((long)bz * 8 + st) * 2048 + qi] = M;
      pl[((long)bz * 8 + st) * 2048 + qi] = L;
    }
  }
}

// Combine the 8 per-s-tile partials into final per-(b,q) stats.
__global__ __launch_bounds__(256)
void stats_reduce(const float* __restrict__ pm, const float* __restrict__ pl,
                  float* __restrict__ mo, float* __restrict__ lo) {
  int idx = blockIdx.x * 256 + threadIdx.x;   // 0..32767
  int b = idx >> 11, q = idx & 2047;
  float M = -3.0e38f, L = 0.f;
  int stmax = q >> 8;
  for (int st = 0; st <= stmax; ++st) {
    float m2 = pm[((long)b * 8 + st) * 2048 + q];
    float l2 = pl[((long)b * 8 + st) * 2048 + q];
    float Mn = fmaxf(M, m2);
    L = L * __expf(M - Mn) + l2 * __expf(m2 - Mn);
    M = Mn;
  }
  mo[(long)b * 2048 + q] = M;
  lo[(long)b * 2048 + q] = L;
}

// normalize att in place ([b][s][q]) and emit bf16 probs [b][q][s].
// Fully-masked 64-tiles inside scores-skipped 256-tiles: att already zeroed
// by the scores dispatch -> only probs zeros (when PV reads them) here.
__global__ void norm_transpose(float* __restrict__ att, const float* __restrict__ ms,
                               const float* __restrict__ ls, u16* __restrict__ probs, int S) {
  int b  = blockIdx.z;
  int q0 = blockIdx.x * 64;
  int s0 = blockIdx.y * 64;
  float* a = att + (long)b * S * S;
  u16* p = probs + (long)b * S * S;
  int tid = threadIdx.x;
  bool needp = s0 < ((q0 & ~255) + 256);   // PV K-cap coverage (256 tiles)

  if (s0 > q0 + 63) {  // fully masked 64-tile
    bool skipped256 = (s0 >> 8) > (q0 >> 8);  // att zeroed by scores already
    if (skipped256 && !needp) return;
    float4 z = make_float4(0.f, 0.f, 0.f, 0.f);
    ushort4 zu; zu.x = zu.y = zu.z = zu.w = 0;
    #pragma unroll
    for (int it = 0; it < 4; ++it) {
      int j = tid + it * 256; int row = j >> 4; int c4 = (j & 15) * 4;
      if (!skipped256) *(float4*)&a[(long)(s0 + row) * S + q0 + c4] = z;
      if (needp) *(ushort4*)&p[(long)(q0 + row) * S + s0 + c4] = zu;
    }
    return;
  }

  __shared__ float t[64][65];
  __shared__ float lm[64], lr[64];
  if (tid < 64) {
    lm[tid] = ms[(long)b * S + q0 + tid];
    lr[tid] = 1.0f / ls[(long)b * S + q0 + tid];
  }
  __syncthreads();

  #pragma unroll
  for (int it = 0; it < 4; ++it) {
    int j = tid + it * 256; int row = j >> 4; int c4 = (j & 15) * 4;
    int s = s0 + row;
    float4 v = *(const float4*)&a[(long)s * S + q0 + c4];
    float vv[4] = {v.x, v.y, v.z, v.w};
    float oo[4];
    #pragma unroll
    for (int e = 0; e < 4; ++e) {
      int q = q0 + c4 + e;
      float pv = (s <= q) ? __expf(vv[e] - lm[c4 + e]) * lr[c4 + e] : 0.0f;
      oo[e] = pv;
      t[row][c4 + e] = pv;
    }
    float4 ov; ov.x = oo[0]; ov.y = oo[1]; ov.z = oo[2]; ov.w = oo[3];
    *(float4*)&a[(long)s * S + q0 + c4] = ov;
  }
  __syncthreads();

  #pragma unroll
  for (int it = 0; it < 4; ++it) {
    int j = tid + it * 256; int qrow = j >> 4; int sc4 = (j & 15) * 4;
    ushort4 ov;
    ov.x = f2bf(t[sc4 + 0][qrow]);
    ov.y = f2bf(t[sc4 + 1][qrow]);
    ov.z = f2bf(t[sc4 + 2][qrow]);
    ov.w = f2bf(t[sc4 + 3][qrow]);
    *(ushort4*)&p[(long)(q0 + qrow) * S + s0 + sc4] = ov;
  }
}

extern "C" void kernel_launch(void* const* d_in, const int* in_sizes, int n_in,
                              void* d_out, int out_size, void* d_ws, size_t ws_size,
                              hipStream_t stream) {
  const int B = 16, S = 2048, H = 1024;
  const long NE = (long)B * S * H;           // 33554432
  const float* Q  = (const float*)d_in[0];
  const float* Kk = (const float*)d_in[1];
  const float* V  = (const float*)d_in[2];
  const float* Wq = (const float*)d_in[3];
  const float* bq = (const float*)d_in[4];
  const float* Wk = (const float*)d_in[5];
  const float* bk = (const float*)d_in[6];
  const float* Wv = (const float*)d_in[7];
  const float* bv = (const float*)d_in[8];

  char* ws = (char*)d_ws;
  u16* xq    = (u16*)ws;                     // 0..64M
  u16* xk    = (u16*)(ws + (64L << 20));     // 64..128M
  u16* xv    = (u16*)(ws + (128L << 20));    // 128..192M
  u16* qb    = (u16*)(ws + (192L << 20));    // 192..256M
  u16* kb    = (u16*)ws;                     // reuse xq (dead after q-proj)
  u16* vT    = (u16*)(ws + (64L << 20));     // reuse xk (dead after k-proj), [B][H][S]
  u16* probs = (u16*)(ws + (128L << 20));    // reuse xv+qb (dead by norm), [B][Q][S]
  u16* Wqb   = (u16*)(ws + (256L << 20));
  u16* Wkb   = (u16*)(ws + (256L << 20) + (2L << 20));
  u16* Wvb   = (u16*)(ws + (256L << 20) + (4L << 20));
  float* mbuf = (float*)(ws + (262L << 20));
  float* lbuf = (float*)(ws + (262L << 20) + (1L << 17));
  float* pm   = (float*)(ws + (263L << 20));   // [B][8][2048] partial m (1MB)
  float* pl   = (float*)(ws + (264L << 20));   // [B][8][2048] partial l (1MB)

  float* ctx = (float*)d_out;            // [B][Q][H]
  float* att = (float*)d_out + NE;       // [B][S][Q]

  // 1) casts fp32 -> bf16
  cast_f32_to_bf16<<<2048, 256, 0, stream>>>(Q,  xq, NE >> 2);
  cast_f32_to_bf16<<<2048, 256, 0, stream>>>(Kk, xk, NE >> 2);
  cast_f32_to_bf16<<<2048, 256, 0, stream>>>(V,  xv, NE >> 2);
  cast_f32_to_bf16<<<512, 256, 0, stream>>>(Wq, Wqb, ((long)H * H) >> 2);
  cast_f32_to_bf16<<<512, 256, 0, stream>>>(Wk, Wkb, ((long)H * H) >> 2);
  cast_f32_to_bf16<<<512, 256, 0, stream>>>(Wv, Wvb, ((long)H * H) >> 2);

  // 2) projections: q = xq@Wq^T+bq -> qb; k -> kb; v computed transposed -> vT
  gemm_nt256<0, 1, 0, 0><<<dim3(4, 128, 1), 512, 0, stream>>>(
      xq, Wqb, qb, bq, nullptr, nullptr, 1.0f, H, 0, 0, 0, H, 4, 128);
  gemm_nt256<0, 1, 0, 0><<<dim3(4, 128, 1), 512, 0, stream>>>(
      xk, Wkb, kb, bk, nullptr, nullptr, 1.0f, H, 0, 0, 0, H, 4, 128);
  gemm_nt256<0, 2, 0, 0><<<dim3(8, 4, 16), 512, 0, stream>>>(
      Wvb, xv, vT, bv, nullptr, nullptr, 1.0f, H, 0, (long)S * H,
      (long)H * S, S, 8, 4);

  // 3) scores^T into att + masked zero-fill + per-tile stats partials
  gemm_nt256<1, 0, 1, 1><<<dim3(8, 8, 16), 512, 0, stream>>>(
      kb, qb, att, nullptr, pm, pl, 0.03125f, H, (long)S * H, (long)S * H,
      (long)S * S, S, 8, 8);

  // 4) combine stats partials
  stats_reduce<<<128, 256, 0, stream>>>(pm, pl, mbuf, lbuf);

  // 5) normalize in place, emit bf16 probs [b][q][s]
  norm_transpose<<<dim3(32, 32, 16), 256, 0, stream>>>(att, mbuf, lbuf, probs, S);

  // 6) context = probs @ v  (PV, causal K cap at m0+256, heavy-first order)
  gemm_nt256<1, 0, 2, 0><<<dim3(4, 8, 16), 512, 0, stream>>>(
      probs, vT, ctx, nullptr, nullptr, nullptr, 1.0f, S, (long)S * S,
      (long)H * S, (long)S * H, H, 4, 8);
}